// Round 23
// baseline (133.283 us; speedup 1.0000x reference)
//
#include <hip/hip_runtime.h>
#include <hip/hip_bf16.h>
#include <stdint.h>

#define T_TOK 8192
#define DIM   1024
#define NEXP  16
#define ESZ   256
#define TOPK  4
#define BK    64
#define NPAIR (T_TOK*TOPK)                 // 32768
#define NBLK  128                          // scatter blocks (256 pairs / 64 tokens)
#define MAXROWS (NPAIR + NEXP*128)         // 34816 (128-padded segments)
#define MAXTILES (NPAIR/128 + NEXP)        // 272 row-tiles of 128
#define NGATEB (T_TOK/16*2)                // 1024 gate sub-blocks
#define NTRB   (8192)                      // transpose sub-blocks (256 x 32)

typedef __hip_bfloat16 bf16;
typedef short bf16x8 __attribute__((ext_vector_type(8)));
typedef float f32x4 __attribute__((ext_vector_type(4)));

__device__ __forceinline__ unsigned short f2bu(float f){
  __hip_bfloat16 b = __float2bfloat16(f);
  return *reinterpret_cast<unsigned short*>(&b);
}
__device__ __forceinline__ float bu2f(unsigned short u){
  __hip_bfloat16 b = *reinterpret_cast<__hip_bfloat16*>(&u);
  return __bfloat162float(b);
}

__device__ __forceinline__ void gload16(const void* g, void* l){
  __builtin_amdgcn_global_load_lds((const __attribute__((address_space(1))) void*)g,
                                   (__attribute__((address_space(3))) void*)l, 16, 0, 0);
}

// ------- fused prep: gate_dot (blocks 0..1023) + weight transposes ----------
// gate: split-K fp32 dot, 2 tokens/thread, wg half in 32KB LDS.
// transpose blocks co-scheduled to fill gate's idle memory/VALU slots.
__global__ __launch_bounds__(256) void k_gate_prep(const float* __restrict__ x,
    const float* __restrict__ wg, const float* __restrict__ keys,
    const float* __restrict__ values, bf16* __restrict__ xb,
    float* __restrict__ plog, bf16* __restrict__ kT, bf16* __restrict__ vT)
{
  __shared__ char smem[32768];
  const int tid = threadIdx.x;

  if (blockIdx.x < NGATEB){
    // ---------------- gate_dot ----------------
    float* wlds = (float*)smem;              // 32 KB: one K-half of wg
    const int half = blockIdx.x & 1;
    const int tg   = blockIdx.x >> 1;        // 16-token group
    {
      const float4* src = (const float4*)wg; // wg[e][d]: e*256 + half*128 + d4
      float4* dst = (float4*)wlds;
#pragma unroll
      for (int i=0;i<8;i++){
        int idx = tid + i*256;               // 0..2047
        int e = idx >> 7, d4 = idx & 127;
        dst[idx] = src[e*256 + half*128 + d4];
      }
    }
    __syncthreads();

    const int ts = tid >> 5;                 // 8 token slots
    const int dc = tid & 31;                 // 32 dim chunks of the half
    const int t0 = tg*16 + ts, t1 = t0 + 8;
    const float* xr0 = x + (size_t)t0*DIM + half*512;
    const float* xr1 = x + (size_t)t1*DIM + half*512;
    unsigned short* xd0 = (unsigned short*)xb + (size_t)t0*DIM + half*512;
    unsigned short* xd1 = (unsigned short*)xb + (size_t)t1*DIM + half*512;

    float acc0[NEXP], acc1[NEXP];
#pragma unroll
    for (int e=0;e<NEXP;e++){ acc0[e]=0.f; acc1[e]=0.f; }

#pragma unroll
    for (int i=0;i<4;i++){
      const int d0 = i*128 + dc*4;
      float4 xv0 = *(const float4*)(xr0 + d0);
      float4 xv1 = *(const float4*)(xr1 + d0);
      ushort4 o0; o0.x=f2bu(xv0.x); o0.y=f2bu(xv0.y); o0.z=f2bu(xv0.z); o0.w=f2bu(xv0.w);
      ushort4 o1; o1.x=f2bu(xv1.x); o1.y=f2bu(xv1.y); o1.z=f2bu(xv1.z); o1.w=f2bu(xv1.w);
      *(ushort4*)(xd0 + d0) = o0;
      *(ushort4*)(xd1 + d0) = o1;
#pragma unroll
      for (int e=0;e<NEXP;e++){
        float4 w = *(const float4*)(wlds + e*512 + d0);
        acc0[e] += xv0.x*w.x + xv0.y*w.y + xv0.z*w.z + xv0.w*w.w;
        acc1[e] += xv1.x*w.x + xv1.y*w.y + xv1.z*w.z + xv1.w*w.w;
      }
    }

#pragma unroll
    for (int e=0;e<NEXP;e++){
#pragma unroll
      for (int s=1;s<32;s<<=1){
        acc0[e] += __shfl_xor(acc0[e], s);
        acc1[e] += __shfl_xor(acc1[e], s);
      }
    }

    if (dc==0){
      float* p0 = plog + (size_t)t0*32 + half*16;
      float* p1 = plog + (size_t)t1*32 + half*16;
#pragma unroll
      for (int i=0;i<4;i++){
        f32x4 v0 = {acc0[i*4],acc0[i*4+1],acc0[i*4+2],acc0[i*4+3]};
        f32x4 v1 = {acc1[i*4],acc1[i*4+1],acc1[i*4+2],acc1[i*4+3]};
        *(f32x4*)(p0 + i*4) = v0;
        *(f32x4*)(p1 + i*4) = v1;
      }
    }
  } else {
    // ---------------- weight transpose ----------------
    float (*tile)[33] = (float(*)[33])smem;  // 4.2 KB of the 32KB block
    const int bid = blockIdx.x - NGATEB;     // 0..8191
    const int by = bid >> 8, bx = bid & 255;
    const int which = by >> 4, e = by & 15;
    const int R = which ? ESZ : DIM, C = which ? DIM : ESZ;
    const float* src = (which ? values : keys) + (size_t)e*DIM*ESZ;
    bf16* dst = (which ? vT : kT) + (size_t)e*DIM*ESZ;
    const int ctiles = C/32;
    const int r0 = (bx / ctiles)*32, c0 = (bx % ctiles)*32;
    const int tx = tid & 31, ty = tid >> 5;
#pragma unroll
    for (int i=0;i<4;i++){ int r = ty + i*8; tile[r][tx] = src[(size_t)(r0+r)*C + c0 + tx]; }
    __syncthreads();
#pragma unroll
    for (int i=0;i<4;i++){ int r = ty + i*8; dst[(size_t)(c0+r)*R + r0 + tx] = __float2bfloat16(tile[tx][r]); }
  }
}

// ------- combine halves -> sigmoid -> top4 -> sel + per-64-token hist -------
__global__ __launch_bounds__(256) void k_gate_top4(const float* __restrict__ plog,
    int* __restrict__ sel_idx, float* __restrict__ sel_gate,
    int* __restrict__ block_hist)
{
  __shared__ int h[4][NEXP];
  const int tid = threadIdx.x;
  if (tid < 64) h[tid>>4][tid&15] = 0;
  __syncthreads();

  const int t = blockIdx.x*256 + tid;
  const float* p = plog + (size_t)t*32;
  float v[NEXP];
#pragma unroll
  for (int i=0;i<4;i++){
    f32x4 a = *(const f32x4*)(p + i*4);
    f32x4 b = *(const f32x4*)(p + 16 + i*4);
#pragma unroll
    for (int j=0;j<4;j++) v[i*4+j] = 1.f/(1.f + expf(-(a[j]+b[j])));
  }
#pragma unroll
  for (int k=0;k<TOPK;k++){
    float bv=-2.f; int bi=0;
#pragma unroll
    for (int e=0;e<NEXP;e++) if (v[e] > bv){ bv=v[e]; bi=e; }
    sel_idx[t*TOPK+k]=bi; sel_gate[t*TOPK+k]=bv;
    atomicAdd(&h[tid>>6][bi],1);
    v[bi] = -2.f;
  }
  __syncthreads();
  if (tid < 64)
    block_hist[((size_t)blockIdx.x*4 + (tid>>4))*NEXP + (tid&15)] = h[tid>>4][tid&15];
}

// ------- totals -> 128-padded segments + tile map + per-scatter-block bases -
__global__ void k_meta(const int* __restrict__ gh,
    int* __restrict__ tile_expert, int* __restrict__ tile_rowstart,
    int* __restrict__ tile_segend, int* __restrict__ block_base)
{
  __shared__ int sbc[NBLK][NEXP];     // per-scatter-block counts (8 KB)
  __shared__ int cnt[NEXP], seg[NEXP];
  const int tid = threadIdx.x;
  for (int cell = tid; cell < NBLK*NEXP; cell += 256)
    sbc[cell>>4][cell&15] = gh[cell];
  __syncthreads();
  if (tid < NEXP){
    int s=0;
    for (int sb=0; sb<NBLK; sb++) s += sbc[sb][tid];
    cnt[tid]=s;
  }
  __syncthreads();
  if (tid==0){
    int off=0, tc=0;
    for (int e=0;e<NEXP;e++){
      seg[e]=off;
      int c = cnt[e];
      int nt = (c + 127)/128;
      for (int i=0;i<nt;i++){
        tile_expert[tc]=e; tile_rowstart[tc]=off+i*128; tile_segend[tc]=off+c; tc++;
      }
      off += nt*128;           // 128-padded segments: tiles never overlap experts
    }
    for (; tc<MAXTILES; tc++) tile_expert[tc]=-1;
  }
  __syncthreads();
  if (tid < NEXP){
    int s = seg[tid];
    for (int sb=0; sb<NBLK; sb++){ block_base[sb*NEXP + tid] = s; s += sbc[sb][tid]; }
  }
}

// ------- deterministic scatter: stores pair id p = token*4+k ----------------
__global__ __launch_bounds__(256) void k_scatter(const int* __restrict__ sel_idx,
    const float* __restrict__ sel_gate, const int* __restrict__ block_base,
    int* __restrict__ assign_pair, float* __restrict__ assign_gate)
{
  __shared__ int wcnt[4][NEXP];
  const int p = blockIdx.x*256 + threadIdx.x;
  const int wave = threadIdx.x >> 6, lane = threadIdx.x & 63;
  const int e = sel_idx[p];
  const float g = sel_gate[p];
  int rank = 0;
#pragma unroll
  for (int ee=0; ee<NEXP; ee++){
    unsigned long long m = __ballot(e==ee);
    if (lane==0) wcnt[wave][ee] = (int)__popcll(m);
    if (e==ee) rank = (int)__popcll(m & ((1ull<<lane)-1ull));
  }
  __syncthreads();
  int pre = 0;
  for (int w=0; w<wave; w++) pre += wcnt[w][e];
  const int row = block_base[blockIdx.x*NEXP + e] + pre + rank;
  assign_pair[row] = p;
  assign_gate[row] = g;
}

// ---------------- GEMM1: h = bf16( relu(Xg @ keys_e) * gate ) ---------------
// 64x128 subtile of a 128-row tile; grid (2, 544): by>>1 = tile, by&1 = half.
__global__ __launch_bounds__(256, 6) void k_gemm1(
    const bf16* __restrict__ xb, const bf16* __restrict__ kT,
    const int* __restrict__ assign_pair, const float* __restrict__ assign_gate,
    const int* __restrict__ tile_expert, const int* __restrict__ tile_rowstart,
    const int* __restrict__ tile_segend, bf16* __restrict__ h)
{
  __shared__ char smem[24576];   // A(8K) B(16K), single buffer
  __shared__ int   tokens_s[64];
  __shared__ float gates_s[64];

  const int nb = blockIdx.x, tile = blockIdx.y >> 1, half = blockIdx.y & 1;
  const int e = tile_expert[tile];
  if (e < 0) return;
  const int row0 = tile_rowstart[tile] + half*64;
  const int segend = tile_segend[tile];
  if (row0 >= segend) return;          // all-padding subtile; gemm2 discards
  const int tid = threadIdx.x, wave = tid>>6, lane = tid&63;

  if (tid < 64){
    int rg = row0 + tid;
    bool vld = rg < segend;
    tokens_s[tid] = vld ? (assign_pair[rg] >> 2) : 0;
    gates_s[tid]  = vld ? assign_gate[rg] : 0.f;
  }
  __syncthreads();

  const bf16* qA[2]; const bf16* qB[4]; int loA[2], loB[4];
#pragma unroll
  for (int i=0;i<2;i++){
    int row = i*32 + wave*8 + (lane>>3);
    int c   = (lane&7) ^ (row&7);               // source-side XOR pre-swizzle
    qA[i] = xb + (size_t)tokens_s[row]*DIM + c*8;
    loA[i] = i*4096 + wave*1024;
  }
#pragma unroll
  for (int i=0;i<4;i++){
    int col = i*32 + wave*8 + (lane>>3);
    int c   = (lane&7) ^ (col&7);
    qB[i] = kT + ((size_t)e*ESZ + nb*128 + col)*DIM + c*8;
    loB[i] = i*4096 + wave*1024;
  }

  const int wr0 = (wave>>1)*32, wc0 = (wave&1)*64;
  int offA[2][2], offB[2][4];                   // K-invariant LDS read offsets
#pragma unroll
  for (int kk=0;kk<2;kk++){
    int kb = kk*64 + (lane>>4)*16;
#pragma unroll
    for (int m=0;m<2;m++){ int row = wr0 + m*16 + (lane&15); offA[kk][m] = row*128 + (kb ^ ((row&7)<<4)); }
#pragma unroll
    for (int n=0;n<4;n++){ int col = wc0 + n*16 + (lane&15); offB[kk][n] = col*128 + (kb ^ ((col&7)<<4)); }
  }

  f32x4 acc[2][4];
#pragma unroll
  for (int m=0;m<2;m++)
#pragma unroll
    for (int n=0;n<4;n++) acc[m][n] = {0.f,0.f,0.f,0.f};

  auto stage = [&](){
#pragma unroll
    for (int i=0;i<2;i++){ gload16(qA[i], smem + loA[i]); qA[i]+=BK; }
#pragma unroll
    for (int i=0;i<4;i++){ gload16(qB[i], smem + 8192 + loB[i]); qB[i]+=BK; }
  };
  auto compute = [&](){
#pragma unroll
    for (int kk=0;kk<2;kk++){
      bf16x8 af[2], bfr[4];
#pragma unroll
      for (int m=0;m<2;m++) af[m]  = *(const bf16x8*)(smem + offA[kk][m]);
#pragma unroll
      for (int n=0;n<4;n++) bfr[n] = *(const bf16x8*)(smem + 8192 + offB[kk][n]);
#pragma unroll
      for (int m=0;m<2;m++)
#pragma unroll
        for (int n=0;n<4;n++)
          acc[m][n] = __builtin_amdgcn_mfma_f32_16x16x32_bf16(af[m], bfr[n], acc[m][n], 0,0,0);
    }
  };

#pragma unroll 1
  for (int kt=0; kt<16; ++kt){
    stage();
    asm volatile("s_waitcnt vmcnt(0)" ::: "memory");
    __builtin_amdgcn_s_barrier();
    compute();
    __builtin_amdgcn_s_barrier();
  }

#pragma unroll
  for (int m=0;m<2;m++)
#pragma unroll
    for (int n=0;n<4;n++){
      int col = wc0 + n*16 + (lane&15);
#pragma unroll
      for (int j=0;j<4;j++){
        int rloc = wr0 + m*16 + ((lane>>4)<<2) + j;
        float v = fmaxf(acc[m][n][j], 0.f) * gates_s[rloc];
        h[(size_t)(row0 + rloc)*ESZ + nb*128 + col] = __float2bfloat16(v);
      }
    }
}

// -------- GEMM2: partial[t*4+k] = bf16( h[row] @ values_e ) -----------------
// 64x128 subtile of a 128-row tile; grid (8, 544). 24KB LDS -> 6 blocks/CU.
__global__ __launch_bounds__(256, 6) void k_gemm2(
    const bf16* __restrict__ h, const bf16* __restrict__ vT,
    const int* __restrict__ assign_pair,
    const int* __restrict__ tile_expert, const int* __restrict__ tile_rowstart,
    const int* __restrict__ tile_segend, bf16* __restrict__ partial)
{
  __shared__ char smem[24576];   // A(8K) B(16K), single buffer
  __shared__ int pairs_s[64];

  const int nb = blockIdx.x, tile = blockIdx.y >> 1, half = blockIdx.y & 1;
  const int e = tile_expert[tile];
  if (e < 0) return;
  const int row0 = tile_rowstart[tile] + half*64;
  const int segend = tile_segend[tile];
  if (row0 >= segend) return;
  const int tid = threadIdx.x, wave = tid>>6, lane = tid&63;

  if (tid < 64){
    int rg = row0 + tid;
    pairs_s[tid] = (rg < segend) ? assign_pair[rg] : -1;
  }
  __syncthreads();

  const bf16* qA[2]; const bf16* qB[4]; int loA[2], loB[4];
#pragma unroll
  for (int i=0;i<2;i++){
    int row = i*32 + wave*8 + (lane>>3);
    int c   = (lane&7) ^ (row&7);
    qA[i] = h + (size_t)(row0 + row)*ESZ + c*8;
    loA[i] = i*4096 + wave*1024;
  }
#pragma unroll
  for (int i=0;i<4;i++){
    int col = i*32 + wave*8 + (lane>>3);
    int c   = (lane&7) ^ (col&7);
    qB[i] = vT + ((size_t)e*DIM + nb*128 + col)*ESZ + c*8;
    loB[i] = i*4096 + wave*1024;
  }

  const int wr0 = (wave>>1)*32, wc0 = (wave&1)*64;
  int offA[2][2], offB[2][4];
#pragma unroll
  for (int kk=0;kk<2;kk++){
    int kb = kk*64 + (lane>>4)*16;
#pragma unroll
    for (int m=0;m<2;m++){ int row = wr0 + m*16 + (lane&15); offA[kk][m] = row*128 + (kb ^ ((row&7)<<4)); }
#pragma unroll
    for (int n=0;n<4;n++){ int col = wc0 + n*16 + (lane&15); offB[kk][n] = col*128 + (kb ^ ((col&7)<<4)); }
  }

  f32x4 acc[2][4];
#pragma unroll
  for (int m=0;m<2;m++)
#pragma unroll
    for (int n=0;n<4;n++) acc[m][n] = {0.f,0.f,0.f,0.f};

  auto stage = [&](){
#pragma unroll
    for (int i=0;i<2;i++){ gload16(qA[i], smem + loA[i]); qA[i]+=BK; }
#pragma unroll
    for (int i=0;i<4;i++){ gload16(qB[i], smem + 8192 + loB[i]); qB[i]+=BK; }
  };
  auto compute = [&](){
#pragma unroll
    for (int kk=0;kk<2;kk++){
      bf16x8 af[2], bfr[4];
#pragma unroll
      for (int m=0;m<2;m++) af[m]  = *(const bf16x8*)(smem + offA[kk][m]);
#pragma unroll
      for (int n=0;n<4;n++) bfr[n] = *(const bf16x8*)(smem + 8192 + offB[kk][n]);
#pragma unroll
      for (int m=0;m<2;m++)
#pragma unroll
        for (int n=0;n<4;n++)
          acc[m][n] = __builtin_amdgcn_mfma_f32_16x16x32_bf16(af[m], bfr[n], acc[m][n], 0,0,0);
    }
  };

#pragma unroll 1
  for (int kt=0; kt<4; ++kt){
    stage();
    asm volatile("s_waitcnt vmcnt(0)" ::: "memory");
    __builtin_amdgcn_s_barrier();
    compute();
    __builtin_amdgcn_s_barrier();
  }

#pragma unroll
  for (int m=0;m<2;m++)
#pragma unroll
    for (int n=0;n<4;n++){
      int col = wc0 + n*16 + (lane&15);
#pragma unroll
      for (int j=0;j<4;j++){
        int rloc = wr0 + m*16 + ((lane>>4)<<2) + j;
        int pp = pairs_s[rloc];
        if (pp >= 0)
          partial[(size_t)pp*DIM + nb*128 + col] = __float2bfloat16(acc[m][n][j]);
      }
    }
}

// -------- reduce: out[t] = sum_k partial[t*4+k]  (fully contiguous) ---------
__global__ __launch_bounds__(256) void k_reduce(const bf16* __restrict__ partial,
    float* __restrict__ out)
{
  const int tb = blockIdx.x*4;
  const int c0 = threadIdx.x * 4;
#pragma unroll
  for (int i=0;i<4;i++){
    const int t = tb + i;
    const unsigned short* pr = (const unsigned short*)partial + (size_t)t*4*DIM;
    float a0=0.f,a1=0.f,a2=0.f,a3=0.f;
#pragma unroll
    for (int k=0;k<TOPK;k++){
      ushort4 v = *(const ushort4*)(pr + k*DIM + c0);
      a0 += bu2f(v.x); a1 += bu2f(v.y); a2 += bu2f(v.z); a3 += bu2f(v.w);
    }
    float4 o = {a0,a1,a2,a3};
    *(float4*)(out + (size_t)t*DIM + c0) = o;
  }
}

// ---------------------------------------------------------------------------
extern "C" void kernel_launch(void* const* d_in, const int* in_sizes, int n_in,
                              void* d_out, int out_size, void* d_ws, size_t ws_size,
                              hipStream_t stream)
{
  const float* x      = (const float*)d_in[0];
  const float* wg     = (const float*)d_in[1];
  const float* keys   = (const float*)d_in[2];
  const float* values = (const float*)d_in[3];
  float* out = (float*)d_out;

  char* ws = (char*)d_ws;
  size_t off = 0;
  bf16* vT   = (bf16*)(ws+off); off += (size_t)NEXP*DIM*ESZ*2;   // 8.4 MB
  bf16* hbuf = (bf16*)(ws+off); off += (size_t)MAXROWS*ESZ*2;    // 17.8 MB
  float* plog         = (float*)(ws+off); off += (size_t)T_TOK*32*4;   // 1 MB
  int*   sel_idx      = (int*)  (ws+off); off += (size_t)NPAIR*4;
  float* sel_gate     = (float*)(ws+off); off += (size_t)NPAIR*4;
  int*   assign_pair  = (int*)  (ws+off); off += (size_t)MAXROWS*4;
  float* assign_gate  = (float*)(ws+off); off += (size_t)MAXROWS*4;
  int*   block_hist   = (int*)  (ws+off); off += (size_t)NBLK*NEXP*4;
  int*   block_base   = (int*)  (ws+off); off += (size_t)NBLK*NEXP*4;
  int*   tile_expert  = (int*)  (ws+off); off += 4096;
  int*   tile_rowstart= (int*)  (ws+off); off += 4096;
  int*   tile_segend  = (int*)  (ws+off); off += 4096;
  // partial is live only AFTER gemm1; xb/kT are dead after gemm1 -> alias them
  // into partial's tail.
  const size_t PARTIAL_BYTES = (size_t)NPAIR*DIM*2;              // 67.1 MB
  const size_t XB_BYTES = (size_t)T_TOK*DIM*2;                   // 16.8 MB
  const size_t KT_BYTES = (size_t)NEXP*ESZ*DIM*2;                // 8.4 MB
  bf16* partial = (bf16*)(ws+off); off += PARTIAL_BYTES;
  bf16* xb = (bf16*)((char*)partial + PARTIAL_BYTES - XB_BYTES - KT_BYTES);
  bf16* kT = (bf16*)((char*)partial + PARTIAL_BYTES - KT_BYTES);

  k_gate_prep<<<NGATEB + NTRB, 256, 0, stream>>>(x, wg, keys, values, xb, plog, kT, vT);
  k_gate_top4<<<T_TOK/256, 256, 0, stream>>>(plog, sel_idx, sel_gate, block_hist);
  k_meta<<<1, 256, 0, stream>>>(block_hist, tile_expert, tile_rowstart, tile_segend, block_base);
  k_scatter<<<NBLK, 256, 0, stream>>>(sel_idx, sel_gate, block_base, assign_pair, assign_gate);
  k_gemm1<<<dim3(2, MAXTILES*2), 256, 0, stream>>>(xb, kT, assign_pair, assign_gate,
      tile_expert, tile_rowstart, tile_segend, hbuf);
  k_gemm2<<<dim3(8, MAXTILES*2), 256, 0, stream>>>(hbuf, vT, assign_pair,
      tile_expert, tile_rowstart, tile_segend, partial);
  k_reduce<<<T_TOK/4, 256, 0, stream>>>(partial, out);
}

// Round 25
// 131.833 us; speedup vs baseline: 1.0110x; 1.0110x over previous
//
#include <hip/hip_runtime.h>
#include <hip/hip_bf16.h>
#include <stdint.h>

#define T_TOK 8192
#define DIM   1024
#define NEXP  16
#define ESZ   256
#define TOPK  4
#define BK    64
#define NPAIR (T_TOK*TOPK)                 // 32768
#define NBLK  128                          // scatter blocks (256 pairs / 64 tokens)
#define MAXROWS (NPAIR + NEXP*128)         // 34816 (128-padded segments)
#define MAXTILES (NPAIR/128 + NEXP)        // 272 row-tiles of 128

typedef __hip_bfloat16 bf16;
typedef short bf16x8 __attribute__((ext_vector_type(8)));
typedef float f32x4 __attribute__((ext_vector_type(4)));

__device__ __forceinline__ unsigned short f2bu(float f){
  __hip_bfloat16 b = __float2bfloat16(f);
  return *reinterpret_cast<unsigned short*>(&b);
}
__device__ __forceinline__ float bu2f(unsigned short u){
  __hip_bfloat16 b = *reinterpret_cast<__hip_bfloat16*>(&u);
  return __bfloat162float(b);
}

__device__ __forceinline__ void gload16(const void* g, void* l){
  __builtin_amdgcn_global_load_lds((const __attribute__((address_space(1))) void*)g,
                                   (__attribute__((address_space(3))) void*)l, 16, 0, 0);
}

// ------- gating dot, split-K fp32: block = (16 tokens, K-half). 32 KB LDS ---
__global__ __launch_bounds__(256) void k_gate_dot(const float* __restrict__ x,
    const float* __restrict__ wg, bf16* __restrict__ xb, float* __restrict__ plog)
{
  __shared__ float wlds[NEXP*512];   // 32 KB: one K-half of wg
  const int tid = threadIdx.x;
  const int half = blockIdx.x & 1;
  const int tg   = blockIdx.x >> 1;          // 16-token group

  {
    const float4* src = (const float4*)wg;   // wg[e][d] fp32: e*256 + half*128 + d4
    float4* dst = (float4*)wlds;
#pragma unroll
    for (int i=0;i<8;i++){
      int idx = tid + i*256;                 // 0..2047
      int e = idx >> 7, d4 = idx & 127;
      dst[idx] = src[e*256 + half*128 + d4];
    }
  }
  __syncthreads();

  const int ts = tid >> 5;                   // 8 token slots
  const int dc = tid & 31;                   // 32 dim chunks of the half
  const int t0 = tg*16 + ts, t1 = t0 + 8;
  const float* xr0 = x + (size_t)t0*DIM + half*512;
  const float* xr1 = x + (size_t)t1*DIM + half*512;
  unsigned short* xd0 = (unsigned short*)xb + (size_t)t0*DIM + half*512;
  unsigned short* xd1 = (unsigned short*)xb + (size_t)t1*DIM + half*512;

  float acc0[NEXP], acc1[NEXP];
#pragma unroll
  for (int e=0;e<NEXP;e++){ acc0[e]=0.f; acc1[e]=0.f; }

#pragma unroll
  for (int i=0;i<4;i++){
    const int d0 = i*128 + dc*4;
    float4 xv0 = *(const float4*)(xr0 + d0);
    float4 xv1 = *(const float4*)(xr1 + d0);
    ushort4 o0; o0.x=f2bu(xv0.x); o0.y=f2bu(xv0.y); o0.z=f2bu(xv0.z); o0.w=f2bu(xv0.w);
    ushort4 o1; o1.x=f2bu(xv1.x); o1.y=f2bu(xv1.y); o1.z=f2bu(xv1.z); o1.w=f2bu(xv1.w);
    *(ushort4*)(xd0 + d0) = o0;
    *(ushort4*)(xd1 + d0) = o1;
#pragma unroll
    for (int e=0;e<NEXP;e++){
      float4 w = *(const float4*)(wlds + e*512 + d0);
      acc0[e] += xv0.x*w.x + xv0.y*w.y + xv0.z*w.z + xv0.w*w.w;
      acc1[e] += xv1.x*w.x + xv1.y*w.y + xv1.z*w.z + xv1.w*w.w;
    }
  }

#pragma unroll
  for (int e=0;e<NEXP;e++){
#pragma unroll
    for (int s=1;s<32;s<<=1){
      acc0[e] += __shfl_xor(acc0[e], s);
      acc1[e] += __shfl_xor(acc1[e], s);
    }
  }

  if (dc==0){
    float* p0 = plog + (size_t)t0*32 + half*16;
    float* p1 = plog + (size_t)t1*32 + half*16;
#pragma unroll
    for (int i=0;i<4;i++){
      f32x4 v0 = {acc0[i*4],acc0[i*4+1],acc0[i*4+2],acc0[i*4+3]};
      f32x4 v1 = {acc1[i*4],acc1[i*4+1],acc1[i*4+2],acc1[i*4+3]};
      *(f32x4*)(p0 + i*4) = v0;
      *(f32x4*)(p1 + i*4) = v1;
    }
  }
}

// ------- combine halves -> sigmoid -> top4 -> sel + per-64-token hist -------
__global__ __launch_bounds__(256) void k_gate_top4(const float* __restrict__ plog,
    int* __restrict__ sel_idx, float* __restrict__ sel_gate,
    int* __restrict__ block_hist)
{
  __shared__ int h[4][NEXP];
  const int tid = threadIdx.x;
  if (tid < 64) h[tid>>4][tid&15] = 0;
  __syncthreads();

  const int t = blockIdx.x*256 + tid;
  const float* p = plog + (size_t)t*32;
  float v[NEXP];
#pragma unroll
  for (int i=0;i<4;i++){
    f32x4 a = *(const f32x4*)(p + i*4);
    f32x4 b = *(const f32x4*)(p + 16 + i*4);
#pragma unroll
    for (int j=0;j<4;j++) v[i*4+j] = 1.f/(1.f + expf(-(a[j]+b[j])));
  }
#pragma unroll
  for (int k=0;k<TOPK;k++){
    float bv=-2.f; int bi=0;
#pragma unroll
    for (int e=0;e<NEXP;e++) if (v[e] > bv){ bv=v[e]; bi=e; }
    sel_idx[t*TOPK+k]=bi; sel_gate[t*TOPK+k]=bv;
    atomicAdd(&h[tid>>6][bi],1);
    v[bi] = -2.f;
  }
  __syncthreads();
  if (tid < 64)
    block_hist[((size_t)blockIdx.x*4 + (tid>>4))*NEXP + (tid&15)] = h[tid>>4][tid&15];
}

// ------- merged fp32->bf16 transposes: keys (z<16) and values (z>=16) -------
__global__ __launch_bounds__(256) void k_transpose2(const float* __restrict__ keys,
    const float* __restrict__ values, bf16* __restrict__ kT, bf16* __restrict__ vT)
{
  __shared__ float tile[32][33];
  const int which = blockIdx.y >> 4, e = blockIdx.y & 15;
  const int R = which ? ESZ : DIM, C = which ? DIM : ESZ;
  const float* src = (which ? values : keys) + (size_t)e*DIM*ESZ;
  bf16* dst = (which ? vT : kT) + (size_t)e*DIM*ESZ;
  const int ctiles = C/32;
  const int r0 = (blockIdx.x / ctiles)*32, c0 = (blockIdx.x % ctiles)*32;
  const int tx = threadIdx.x & 31, ty = threadIdx.x >> 5;
#pragma unroll
  for (int i=0;i<4;i++){ int r = ty + i*8; tile[r][tx] = src[(size_t)(r0+r)*C + c0 + tx]; }
  __syncthreads();
#pragma unroll
  for (int i=0;i<4;i++){ int r = ty + i*8; dst[(size_t)(c0+r)*R + r0 + tx] = __float2bfloat16(tile[tx][r]); }
}

// ------- totals -> 128-padded segments + tile map + per-scatter-block bases -
__global__ void k_meta(const int* __restrict__ gh,
    int* __restrict__ tile_expert, int* __restrict__ tile_rowstart,
    int* __restrict__ tile_segend, int* __restrict__ block_base)
{
  __shared__ int sbc[NBLK][NEXP];     // per-scatter-block counts (8 KB)
  __shared__ int cnt[NEXP], seg[NEXP];
  const int tid = threadIdx.x;
  for (int cell = tid; cell < NBLK*NEXP; cell += 256)
    sbc[cell>>4][cell&15] = gh[cell];
  __syncthreads();
  if (tid < NEXP){
    int s=0;
    for (int sb=0; sb<NBLK; sb++) s += sbc[sb][tid];
    cnt[tid]=s;
  }
  __syncthreads();
  if (tid==0){
    int off=0, tc=0;
    for (int e=0;e<NEXP;e++){
      seg[e]=off;
      int c = cnt[e];
      int nt = (c + 127)/128;
      for (int i=0;i<nt;i++){
        tile_expert[tc]=e; tile_rowstart[tc]=off+i*128; tile_segend[tc]=off+c; tc++;
      }
      off += nt*128;           // 128-padded segments: tiles never overlap experts
    }
    for (; tc<MAXTILES; tc++) tile_expert[tc]=-1;
  }
  __syncthreads();
  if (tid < NEXP){
    int s = seg[tid];
    for (int sb=0; sb<NBLK; sb++){ block_base[sb*NEXP + tid] = s; s += sbc[sb][tid]; }
  }
}

// ------- deterministic scatter: stores pair id p = token*4+k ----------------
__global__ __launch_bounds__(256) void k_scatter(const int* __restrict__ sel_idx,
    const float* __restrict__ sel_gate, const int* __restrict__ block_base,
    int* __restrict__ assign_pair, float* __restrict__ assign_gate)
{
  __shared__ int wcnt[4][NEXP];
  const int p = blockIdx.x*256 + threadIdx.x;
  const int wave = threadIdx.x >> 6, lane = threadIdx.x & 63;
  const int e = sel_idx[p];
  const float g = sel_gate[p];
  int rank = 0;
#pragma unroll
  for (int ee=0; ee<NEXP; ee++){
    unsigned long long m = __ballot(e==ee);
    if (lane==0) wcnt[wave][ee] = (int)__popcll(m);
    if (e==ee) rank = (int)__popcll(m & ((1ull<<lane)-1ull));
  }
  __syncthreads();
  int pre = 0;
  for (int w=0; w<wave; w++) pre += wcnt[w][e];
  const int row = block_base[blockIdx.x*NEXP + e] + pre + rank;
  assign_pair[row] = p;
  assign_gate[row] = g;
}

// ---------------- GEMM1: h = bf16( relu(Xg @ keys_e) * gate ) ---------------
// 64x128 subtile of a 128-row tile; grid (2, 544): by>>1 = tile, by&1 = half.
__global__ __launch_bounds__(256, 6) void k_gemm1(
    const bf16* __restrict__ xb, const bf16* __restrict__ kT,
    const int* __restrict__ assign_pair, const float* __restrict__ assign_gate,
    const int* __restrict__ tile_expert, const int* __restrict__ tile_rowstart,
    const int* __restrict__ tile_segend, bf16* __restrict__ h)
{
  __shared__ char smem[24576];   // A(8K) B(16K), single buffer
  __shared__ int   tokens_s[64];
  __shared__ float gates_s[64];

  const int nb = blockIdx.x, tile = blockIdx.y >> 1, half = blockIdx.y & 1;
  const int e = tile_expert[tile];
  if (e < 0) return;
  const int row0 = tile_rowstart[tile] + half*64;
  const int segend = tile_segend[tile];
  if (row0 >= segend) return;          // all-padding subtile; gemm2 discards
  const int tid = threadIdx.x, wave = tid>>6, lane = tid&63;

  if (tid < 64){
    int rg = row0 + tid;
    bool vld = rg < segend;
    tokens_s[tid] = vld ? (assign_pair[rg] >> 2) : 0;
    gates_s[tid]  = vld ? assign_gate[rg] : 0.f;
  }
  __syncthreads();

  const bf16* qA[2]; const bf16* qB[4]; int loA[2], loB[4];
#pragma unroll
  for (int i=0;i<2;i++){
    int row = i*32 + wave*8 + (lane>>3);
    int c   = (lane&7) ^ (row&7);               // source-side XOR pre-swizzle
    qA[i] = xb + (size_t)tokens_s[row]*DIM + c*8;
    loA[i] = i*4096 + wave*1024;
  }
#pragma unroll
  for (int i=0;i<4;i++){
    int col = i*32 + wave*8 + (lane>>3);
    int c   = (lane&7) ^ (col&7);
    qB[i] = kT + ((size_t)e*ESZ + nb*128 + col)*DIM + c*8;
    loB[i] = i*4096 + wave*1024;
  }

  const int wr0 = (wave>>1)*32, wc0 = (wave&1)*64;
  int offA[2][2], offB[2][4];                   // K-invariant LDS read offsets
#pragma unroll
  for (int kk=0;kk<2;kk++){
    int kb = kk*64 + (lane>>4)*16;
#pragma unroll
    for (int m=0;m<2;m++){ int row = wr0 + m*16 + (lane&15); offA[kk][m] = row*128 + (kb ^ ((row&7)<<4)); }
#pragma unroll
    for (int n=0;n<4;n++){ int col = wc0 + n*16 + (lane&15); offB[kk][n] = col*128 + (kb ^ ((col&7)<<4)); }
  }

  f32x4 acc[2][4];
#pragma unroll
  for (int m=0;m<2;m++)
#pragma unroll
    for (int n=0;n<4;n++) acc[m][n] = {0.f,0.f,0.f,0.f};

  auto stage = [&](){
#pragma unroll
    for (int i=0;i<2;i++){ gload16(qA[i], smem + loA[i]); qA[i]+=BK; }
#pragma unroll
    for (int i=0;i<4;i++){ gload16(qB[i], smem + 8192 + loB[i]); qB[i]+=BK; }
  };
  auto compute = [&](){
#pragma unroll
    for (int kk=0;kk<2;kk++){
      bf16x8 af[2], bfr[4];
#pragma unroll
      for (int m=0;m<2;m++) af[m]  = *(const bf16x8*)(smem + offA[kk][m]);
#pragma unroll
      for (int n=0;n<4;n++) bfr[n] = *(const bf16x8*)(smem + 8192 + offB[kk][n]);
#pragma unroll
      for (int m=0;m<2;m++)
#pragma unroll
        for (int n=0;n<4;n++)
          acc[m][n] = __builtin_amdgcn_mfma_f32_16x16x32_bf16(af[m], bfr[n], acc[m][n], 0,0,0);
    }
  };

#pragma unroll 1
  for (int kt=0; kt<16; ++kt){
    stage();
    asm volatile("s_waitcnt vmcnt(0)" ::: "memory");
    __builtin_amdgcn_s_barrier();
    compute();
    __builtin_amdgcn_s_barrier();
  }

#pragma unroll
  for (int m=0;m<2;m++)
#pragma unroll
    for (int n=0;n<4;n++){
      int col = wc0 + n*16 + (lane&15);
#pragma unroll
      for (int j=0;j<4;j++){
        int rloc = wr0 + m*16 + ((lane>>4)<<2) + j;
        float v = fmaxf(acc[m][n][j], 0.f) * gates_s[rloc];
        h[(size_t)(row0 + rloc)*ESZ + nb*128 + col] = __float2bfloat16(v);
      }
    }
}

// -------- GEMM2: partial[t*4+k] = bf16( h[row] @ values_e ) -----------------
// 64x128 subtile of a 128-row tile; grid (8, 544). 24KB LDS -> 6 blocks/CU.
__global__ __launch_bounds__(256, 6) void k_gemm2(
    const bf16* __restrict__ h, const bf16* __restrict__ vT,
    const int* __restrict__ assign_pair,
    const int* __restrict__ tile_expert, const int* __restrict__ tile_rowstart,
    const int* __restrict__ tile_segend, bf16* __restrict__ partial)
{
  __shared__ char smem[24576];   // A(8K) B(16K), single buffer
  __shared__ int pairs_s[64];

  const int nb = blockIdx.x, tile = blockIdx.y >> 1, half = blockIdx.y & 1;
  const int e = tile_expert[tile];
  if (e < 0) return;
  const int row0 = tile_rowstart[tile] + half*64;
  const int segend = tile_segend[tile];
  if (row0 >= segend) return;
  const int tid = threadIdx.x, wave = tid>>6, lane = tid&63;

  if (tid < 64){
    int rg = row0 + tid;
    pairs_s[tid] = (rg < segend) ? assign_pair[rg] : -1;
  }
  __syncthreads();

  const bf16* qA[2]; const bf16* qB[4]; int loA[2], loB[4];
#pragma unroll
  for (int i=0;i<2;i++){
    int row = i*32 + wave*8 + (lane>>3);
    int c   = (lane&7) ^ (row&7);
    qA[i] = h + (size_t)(row0 + row)*ESZ + c*8;
    loA[i] = i*4096 + wave*1024;
  }
#pragma unroll
  for (int i=0;i<4;i++){
    int col = i*32 + wave*8 + (lane>>3);
    int c   = (lane&7) ^ (col&7);
    qB[i] = vT + ((size_t)e*DIM + nb*128 + col)*ESZ + c*8;
    loB[i] = i*4096 + wave*1024;
  }

  const int wr0 = (wave>>1)*32, wc0 = (wave&1)*64;
  int offA[2][2], offB[2][4];
#pragma unroll
  for (int kk=0;kk<2;kk++){
    int kb = kk*64 + (lane>>4)*16;
#pragma unroll
    for (int m=0;m<2;m++){ int row = wr0 + m*16 + (lane&15); offA[kk][m] = row*128 + (kb ^ ((row&7)<<4)); }
#pragma unroll
    for (int n=0;n<4;n++){ int col = wc0 + n*16 + (lane&15); offB[kk][n] = col*128 + (kb ^ ((col&7)<<4)); }
  }

  f32x4 acc[2][4];
#pragma unroll
  for (int m=0;m<2;m++)
#pragma unroll
    for (int n=0;n<4;n++) acc[m][n] = {0.f,0.f,0.f,0.f};

  auto stage = [&](){
#pragma unroll
    for (int i=0;i<2;i++){ gload16(qA[i], smem + loA[i]); qA[i]+=BK; }
#pragma unroll
    for (int i=0;i<4;i++){ gload16(qB[i], smem + 8192 + loB[i]); qB[i]+=BK; }
  };
  auto compute = [&](){
#pragma unroll
    for (int kk=0;kk<2;kk++){
      bf16x8 af[2], bfr[4];
#pragma unroll
      for (int m=0;m<2;m++) af[m]  = *(const bf16x8*)(smem + offA[kk][m]);
#pragma unroll
      for (int n=0;n<4;n++) bfr[n] = *(const bf16x8*)(smem + 8192 + offB[kk][n]);
#pragma unroll
      for (int m=0;m<2;m++)
#pragma unroll
        for (int n=0;n<4;n++)
          acc[m][n] = __builtin_amdgcn_mfma_f32_16x16x32_bf16(af[m], bfr[n], acc[m][n], 0,0,0);
    }
  };

#pragma unroll 1
  for (int kt=0; kt<4; ++kt){
    stage();
    asm volatile("s_waitcnt vmcnt(0)" ::: "memory");
    __builtin_amdgcn_s_barrier();
    compute();
    __builtin_amdgcn_s_barrier();
  }

#pragma unroll
  for (int m=0;m<2;m++)
#pragma unroll
    for (int n=0;n<4;n++){
      int col = wc0 + n*16 + (lane&15);
#pragma unroll
      for (int j=0;j<4;j++){
        int rloc = wr0 + m*16 + ((lane>>4)<<2) + j;
        int pp = pairs_s[rloc];
        if (pp >= 0)
          partial[(size_t)pp*DIM + nb*128 + col] = __float2bfloat16(acc[m][n][j]);
      }
    }
}

// -------- reduce: out[t] = sum_k partial[t*4+k]  (fully contiguous) ---------
__global__ __launch_bounds__(256) void k_reduce(const bf16* __restrict__ partial,
    float* __restrict__ out)
{
  const int tb = blockIdx.x*4;
  const int c0 = threadIdx.x * 4;
#pragma unroll
  for (int i=0;i<4;i++){
    const int t = tb + i;
    const unsigned short* pr = (const unsigned short*)partial + (size_t)t*4*DIM;
    float a0=0.f,a1=0.f,a2=0.f,a3=0.f;
#pragma unroll
    for (int k=0;k<TOPK;k++){
      ushort4 v = *(const ushort4*)(pr + k*DIM + c0);
      a0 += bu2f(v.x); a1 += bu2f(v.y); a2 += bu2f(v.z); a3 += bu2f(v.w);
    }
    float4 o = {a0,a1,a2,a3};
    *(float4*)(out + (size_t)t*DIM + c0) = o;
  }
}

// ---------------------------------------------------------------------------
extern "C" void kernel_launch(void* const* d_in, const int* in_sizes, int n_in,
                              void* d_out, int out_size, void* d_ws, size_t ws_size,
                              hipStream_t stream)
{
  const float* x      = (const float*)d_in[0];
  const float* wg     = (const float*)d_in[1];
  const float* keys   = (const float*)d_in[2];
  const float* values = (const float*)d_in[3];
  float* out = (float*)d_out;

  char* ws = (char*)d_ws;
  size_t off = 0;
  bf16* vT   = (bf16*)(ws+off); off += (size_t)NEXP*DIM*ESZ*2;   // 8.4 MB
  bf16* hbuf = (bf16*)(ws+off); off += (size_t)MAXROWS*ESZ*2;    // 17.8 MB
  float* plog         = (float*)(ws+off); off += (size_t)T_TOK*32*4;   // 1 MB
  int*   sel_idx      = (int*)  (ws+off); off += (size_t)NPAIR*4;
  float* sel_gate     = (float*)(ws+off); off += (size_t)NPAIR*4;
  int*   assign_pair  = (int*)  (ws+off); off += (size_t)MAXROWS*4;
  float* assign_gate  = (float*)(ws+off); off += (size_t)MAXROWS*4;
  int*   block_hist   = (int*)  (ws+off); off += (size_t)NBLK*NEXP*4;
  int*   block_base   = (int*)  (ws+off); off += (size_t)NBLK*NEXP*4;
  int*   tile_expert  = (int*)  (ws+off); off += 4096;
  int*   tile_rowstart= (int*)  (ws+off); off += 4096;
  int*   tile_segend  = (int*)  (ws+off); off += 4096;
  // partial is live only AFTER gemm1; xb/kT are dead after gemm1 -> alias them
  // into partial's tail.
  const size_t PARTIAL_BYTES = (size_t)NPAIR*DIM*2;              // 67.1 MB
  const size_t XB_BYTES = (size_t)T_TOK*DIM*2;                   // 16.8 MB
  const size_t KT_BYTES = (size_t)NEXP*ESZ*DIM*2;                // 8.4 MB
  bf16* partial = (bf16*)(ws+off); off += PARTIAL_BYTES;
  bf16* xb = (bf16*)((char*)partial + PARTIAL_BYTES - XB_BYTES - KT_BYTES);
  bf16* kT = (bf16*)((char*)partial + PARTIAL_BYTES - KT_BYTES);

  k_gate_dot<<<T_TOK/16*2, 256, 0, stream>>>(x, wg, xb, plog);
  k_gate_top4<<<T_TOK/256, 256, 0, stream>>>(plog, sel_idx, sel_gate, block_hist);
  k_transpose2<<<dim3(256, NEXP*2), 256, 0, stream>>>(keys, values, kT, vT);
  k_meta<<<1, 256, 0, stream>>>(block_hist, tile_expert, tile_rowstart, tile_segend, block_base);
  k_scatter<<<NBLK, 256, 0, stream>>>(sel_idx, sel_gate, block_base, assign_pair, assign_gate);
  k_gemm1<<<dim3(2, MAXTILES*2), 256, 0, stream>>>(xb, kT, assign_pair, assign_gate,
      tile_expert, tile_rowstart, tile_segend, hbuf);
  k_gemm2<<<dim3(8, MAXTILES*2), 256, 0, stream>>>(hbuf, vT, assign_pair,
      tile_expert, tile_rowstart, tile_segend, partial);
  k_reduce<<<T_TOK/4, 256, 0, stream>>>(partial, out);
}